// Round 17
// baseline (132.989 us; speedup 1.0000x reference)
//
#include <hip/hip_runtime.h>
#include <hip/hip_bf16.h>

#define B_  2
#define S_  2048
#define D_  1024
#define H_  16
#define DH_ 64
#define M_  (B_ * S_)       // 4096
#define QKV_LD (3 * D_)     // 3072

typedef __bf16 bf16x8 __attribute__((ext_vector_type(8)));
typedef float  f32x4  __attribute__((ext_vector_type(4)));
typedef unsigned short us4 __attribute__((ext_vector_type(4)));
typedef unsigned short us8 __attribute__((ext_vector_type(8)));

__device__ inline unsigned short f2bf(float f) {
  union { __bf16 h; unsigned short u; } cv; cv.h = (__bf16)f; return cv.u;
}
__device__ inline float bf2f(unsigned short u) {
  union { unsigned int i; float f; } cv; cv.i = ((unsigned int)u) << 16; return cv.f;
}
__device__ inline unsigned int pk2bf(float lo, float hi) {
  return (unsigned int)f2bf(lo) | ((unsigned int)f2bf(hi) << 16);
}
// typed stores: bf16 does the BIT conversion (round-3 bug: (unsigned short)v
// was an int conversion -> output was all-zero)
__device__ inline void cstore(float* p, float v) { *p = v; }
__device__ inline void cstore(unsigned short* p, float v) { *p = f2bf(v); }

__device__ inline void gload_lds16(const void* g, void* lds) {
  __builtin_amdgcn_global_load_lds(
      (const __attribute__((address_space(1))) unsigned int*)g,
      (__attribute__((address_space(3))) unsigned int*)lds, 16, 0, 0);
}

// ---------------- fused prep: x->bf16, W_qkv^T->bf16, W_out^T->bf16 ----------------
__global__ __launch_bounds__(256) void prep_all(
    const float* __restrict__ x, unsigned short* __restrict__ x_bf,
    const float* __restrict__ W_qkv, unsigned short* __restrict__ wqkvT,
    const float* __restrict__ W_out, unsigned short* __restrict__ woutT) {
  __shared__ float tile[32][33];
  const int blk = blockIdx.x;
  const int t = threadIdx.x;
  if (blk < 4096) {                       // conv x -> bf16, 4 floats/thread
    int i = blk * 256 + t;
    float4 v = ((const float4*)x)[i];
    us4 p = { f2bf(v.x), f2bf(v.y), f2bf(v.z), f2bf(v.w) };
    ((us4*)x_bf)[i] = p;
    return;
  }
  const float* W; unsigned short* Wt; int K, N, bi;
  if (blk < 4096 + 3072) { bi = blk - 4096; W = W_qkv; Wt = wqkvT; K = D_; N = QKV_LD; }
  else                   { bi = blk - 7168; W = W_out; Wt = woutT; K = D_; N = D_; }
  const int bx = bi % (N / 32), by = bi / (N / 32);
  const int tx = t & 31, ty = t >> 5;
  const int c0 = bx * 32, r0 = by * 32;
  #pragma unroll
  for (int i = 0; i < 4; ++i)
    tile[ty + 8 * i][tx] = W[(size_t)(r0 + ty + 8 * i) * N + c0 + tx];
  __syncthreads();
  #pragma unroll
  for (int i = 0; i < 4; ++i)
    Wt[(size_t)(c0 + ty + 8 * i) * K + r0 + tx] = f2bf(tile[tx][ty + 8 * i]);
}

// ---------------- bf16 MFMA GEMM (m97 structure + T1 XCD swizzle) ----------------
template<typename CT>
__global__ __launch_bounds__(256) void gemm_bf16_tn(
    const unsigned short* __restrict__ A,   // [M][K] bf16
    const unsigned short* __restrict__ Bt,  // [N][K] bf16
    const float* __restrict__ bias,
    CT* __restrict__ C, int N, int K) {
  __shared__ __align__(16) unsigned short smA[128 * 32];
  __shared__ __align__(16) unsigned short smB[128 * 32];
  const int t = threadIdx.x;
  const int w = t >> 6, l = t & 63;
  const int lg = l >> 4, lr = l & 15;
  // XCD swizzle (nwg % 8 == 0 for both GEMMs)
  const int nwg  = gridDim.x * gridDim.y;
  const int bid0 = blockIdx.y * gridDim.x + blockIdx.x;
  const int swz  = (bid0 & 7) * (nwg >> 3) + (bid0 >> 3);
  const int bx = swz % gridDim.x, by = swz / gridDim.x;
  const int row0 = by * 128, col0 = bx * 128;
  const int wm = (w >> 1) * 64, wn = (w & 1) * 64;

  f32x4 acc[4][4] = {};

  for (int k0 = 0; k0 < K; k0 += 32) {
    __syncthreads();  // previous iteration's fragment reads complete
    #pragma unroll
    for (int i = 0; i < 2; ++i) {
      const int inst = 2 * w + i;
      const int r = inst * 16 + (l >> 2);
      const int cb = (l & 3) * 8;  // k-chunk of 8 bf16
      gload_lds16(A  + (size_t)(row0 + r) * K + k0 + cb, &smA[inst * 512]);
      gload_lds16(Bt + (size_t)(col0 + r) * K + k0 + cb, &smB[inst * 512]);
    }
    __syncthreads();  // waits vmcnt(0): tiles resident

    bf16x8 af[4], bfr[4];
    #pragma unroll
    for (int m = 0; m < 4; ++m)
      af[m] = *(const bf16x8*)&smA[(wm + m * 16 + lr) * 32 + lg * 8];
    #pragma unroll
    for (int n = 0; n < 4; ++n)
      bfr[n] = *(const bf16x8*)&smB[(wn + n * 16 + lr) * 32 + lg * 8];
    #pragma unroll
    for (int m = 0; m < 4; ++m)
      #pragma unroll
      for (int n = 0; n < 4; ++n)
        acc[m][n] = __builtin_amdgcn_mfma_f32_16x16x32_bf16(af[m], bfr[n], acc[m][n], 0, 0, 0);
  }

  #pragma unroll
  for (int m = 0; m < 4; ++m) {
    #pragma unroll
    for (int n = 0; n < 4; ++n) {
      const int col = col0 + wn + n * 16 + lr;
      const float bv = bias[col];
      #pragma unroll
      for (int r = 0; r < 4; ++r) {
        const int row = row0 + wm + m * 16 + lg * 4 + r;
        cstore(&C[(size_t)row * N + col], acc[m][n][r] + bv);
      }
    }
  }
}

// ---------------- Causal flash attention, bf16 MFMA, 32 q-rows/wave ----------------
// r13 machinery (KVBLK=64, sigma-permuted K, XOR swizzle, log2 softmax,
// defer-max, T14 staging, 1 barrier/tile, XCD-pinned bh) restructured so
// EACH WAVE owns 16 rows of q-tile lo=x AND 16 rows of hi=31-x: every
// K/V fragment read from LDS feeds 2 MFMAs (hi always, lo while kti<=x)
// -> compute-per-LDS-byte doubles (r16 analysis: LDS BW was the floor).
// 512 blocks x 256 threads (4 waves), 2 blocks/CU; all threads stage.
// [r16 lesson: KVBLK=128 regressed -- V 256B-row reads XOR-collide on the
//  ks bit -> 2.2e6 conflicts; reverted to the conflict-free 64-wide tiles.]
// sigma(rho) = 32*(rho>>5)+8*((rho>>2)&3)+4*((rho>>4)&1)+(rho&3).
__global__ __launch_bounds__(256, 2) void attn_fwd_mfma(
    const unsigned short* __restrict__ qkv, unsigned short* __restrict__ attn_out) {
  const int bid = blockIdx.x;           // 0..511
  const int xcd = bid & 7;
  const int li  = bid >> 3;             // 0..63 within XCD
  const int bh  = xcd * 4 + (li >> 4);  // 4 bh per XCD
  const int x   = li & 15;              // pair index: lo q-tile x, hi 31-x
  const int b = bh / H_, h = bh % H_;
  const unsigned short* base = qkv + (size_t)b * S_ * QKV_LD;

  __shared__ __align__(16) char smK[2][64 * 128];  // K tile [sigma-row][d], XOR-swizzled
  __shared__ __align__(16) char smV[2][64 * 128];  // V^T tile [d][k]

  const int t  = threadIdx.x;           // 0..255
  const int wq = t >> 6;                // wave 0..3
  const int l  = t & 63;
  const int lg = l >> 4;
  const int lr = l & 15;

  const int qlo0 = 64 * x + wq * 16;         // wave's lo rows
  const int qhi0 = 64 * (31 - x) + wq * 16;  // wave's hi rows

  const unsigned short* kbase = base + D_ + h * DH_;
  const unsigned short* vbase = base + 2 * D_ + h * DH_;

  // staging (all 256 threads): T14 async split, issue early / write late
  us8 kreg[2], vreg[2];
  const int kp  = (t & 31) * 2;          // V: pair of k-columns
  const int vdb = ((t >> 5) & 7) * 8;    // V: 8 d-rows

  auto issue_loads = [&](int k0) {
    #pragma unroll
    for (int it = 0; it < 2; ++it) {
      int idx = t + it * 256;
      int r = idx >> 3, c = idx & 7;
      kreg[it] = *(const us8*)(kbase + (size_t)(k0 + r) * QKV_LD + c * 8);
    }
    vreg[0] = *(const us8*)(vbase + (size_t)(k0 + kp) * QKV_LD + vdb);
    vreg[1] = *(const us8*)(vbase + (size_t)(k0 + kp + 1) * QKV_LD + vdb);
  };
  auto write_lds = [&](int buf) {
    #pragma unroll
    for (int it = 0; it < 2; ++it) {
      int idx = t + it * 256;
      int r = idx >> 3, c = idx & 7;
      // sigma^-1: global k-row r -> LDS row rho (pure bit permutation)
      int rho = (r & 0x23) | ((r & 0x04) << 2) | ((r & 0x18) >> 1);
      *(us8*)(smK[buf] + rho * 128 + ((c * 16) ^ ((rho & 7) << 4))) = kreg[it];
    }
    #pragma unroll
    for (int j = 0; j < 8; ++j) {
      int row = vdb + j;
      unsigned int pv = (unsigned int)vreg[0][j] | ((unsigned int)vreg[1][j] << 16);
      *(unsigned int*)(smV[buf] + row * 128 + ((2 * kp) ^ ((row & 7) << 4))) = pv;
    }
  };

  // ---- Q fragments (scale = 1/8 * log2(e): softmax in log2 domain) ----
  bf16x8 qflo[2], qfhi[2];
  #pragma unroll
  for (int p = 0; p < 2; ++p) {
    const int q0 = p ? qhi0 : qlo0;
    const unsigned short* qp = base + (size_t)(q0 + lr) * QKV_LD + h * DH_ + 8 * lg;
    #pragma unroll
    for (int ks = 0; ks < 2; ++ks) {
      us8 qv = *(const us8*)(qp + 32 * ks);
      #pragma unroll
      for (int e = 0; e < 8; ++e)
        (p ? qfhi : qflo)[ks][e] = (__bf16)(bf2f(qv[e]) * 0.18033688f);
    }
  }

  float mlo = -1e30f, llo = 0.f;   // lane's lo q-row = qlo0 + lr
  float mhi = -1e30f, lhi = 0.f;   // lane's hi q-row = qhi0 + lr
  f32x4 alo[4] = {}, ahi[4] = {};

  // softmax (log2 domain, defer-max) + pack for one part; sc -> pa
  auto softmax_pack = [&](f32x4 (&sc)[4], float& mrun, float& lrun,
                          f32x4 (&acc)[4], unsigned int (&pau)[2][4]) {
    float v = fmaxf(fmaxf(sc[0][0], sc[0][1]), fmaxf(sc[0][2], sc[0][3]));
    #pragma unroll
    for (int kt = 1; kt < 4; ++kt)
      v = fmaxf(v, fmaxf(fmaxf(sc[kt][0], sc[kt][1]), fmaxf(sc[kt][2], sc[kt][3])));
    v = fmaxf(v, __shfl_xor(v, 16));
    v = fmaxf(v, __shfl_xor(v, 32));
    if (!__all(v <= mrun + 8.0f)) {     // T13 defer-max
      const float mnew = fmaxf(mrun, v);
      const float alpha = exp2f(mrun - mnew);
      mrun = mnew;
      float alphaO[4];
      #pragma unroll
      for (int r = 0; r < 4; ++r)
        alphaO[r] = __shfl(alpha, (l & 48) | (lg * 4 + r));
      #pragma unroll
      for (int dt = 0; dt < 4; ++dt)
        #pragma unroll
        for (int r = 0; r < 4; ++r) acc[dt][r] *= alphaO[r];
      lrun *= alpha;
    }
    float s = 0.f;
    #pragma unroll
    for (int kt = 0; kt < 4; ++kt)
      #pragma unroll
      for (int r = 0; r < 4; ++r) {
        float p = exp2f(sc[kt][r] - mrun);
        sc[kt][r] = p;
        s += p;
      }
    s += __shfl_xor(s, 16);
    s += __shfl_xor(s, 32);
    lrun += s;
    #pragma unroll
    for (int ks = 0; ks < 2; ++ks) {
      pau[ks][0] = pk2bf(sc[2 * ks][0], sc[2 * ks][1]);
      pau[ks][1] = pk2bf(sc[2 * ks][2], sc[2 * ks][3]);
      pau[ks][2] = pk2bf(sc[2 * ks + 1][0], sc[2 * ks + 1][1]);
      pau[ks][3] = pk2bf(sc[2 * ks + 1][2], sc[2 * ks + 1][3]);
    }
  };

  const int ntiles = 32 - x;   // hi's tile count (superset of lo's x+1)
  issue_loads(0);
  write_lds(0);
  __syncthreads();

  for (int kti = 0; kti < ntiles; ++kti) {
    const int k0 = kti * 64;
    const int cur = kti & 1;
    const bool lo_act = (kti <= x);    // block-uniform

    if (kti + 1 < ntiles) issue_loads((kti + 1) * 64);

    // ---- swapped QK^T on sigma-permuted K rows: K-frag read ONCE, 2 MFMAs ----
    f32x4 schi[4], sclo[4];
    #pragma unroll
    for (int kt = 0; kt < 4; ++kt) {
      schi[kt] = f32x4{0.f, 0.f, 0.f, 0.f};
      sclo[kt] = f32x4{0.f, 0.f, 0.f, 0.f};
      #pragma unroll
      for (int ks = 0; ks < 2; ++ks) {
        int row = kt * 16 + lr;
        bf16x8 kb_ = *(const bf16x8*)(smK[cur] + row * 128 +
                                      (((ks * 64) + 16 * lg) ^ ((row & 7) << 4)));
        schi[kt] = __builtin_amdgcn_mfma_f32_16x16x32_bf16(kb_, qfhi[ks], schi[kt], 0, 0, 0);
        if (lo_act)
          sclo[kt] = __builtin_amdgcn_mfma_f32_16x16x32_bf16(kb_, qflo[ks], sclo[kt], 0, 0, 0);
      }
    }

    // ---- causal masks (true k = k0+32*(kt>>1)+8*lg+4*(kt&1)+r) ----
    if (kti == ntiles - 1) {
      #pragma unroll
      for (int kt = 0; kt < 4; ++kt)
        #pragma unroll
        for (int r = 0; r < 4; ++r) {
          int kc = k0 + ((kt >> 1) << 5) + (lg << 3) + ((kt & 1) << 2) + r;
          if (kc > qhi0 + lr) schi[kt][r] = -1e30f;
        }
    }
    if (lo_act && kti == x) {
      #pragma unroll
      for (int kt = 0; kt < 4; ++kt)
        #pragma unroll
        for (int r = 0; r < 4; ++r) {
          int kc = k0 + ((kt >> 1) << 5) + (lg << 3) + ((kt & 1) << 2) + r;
          if (kc > qlo0 + lr) sclo[kt][r] = -1e30f;
        }
    }

    // ---- softmax + pack (hi always, lo when active) ----
    unsigned int pahi[2][4], palo[2][4];
    softmax_pack(schi, mhi, lhi, ahi, pahi);
    if (lo_act) softmax_pack(sclo, mlo, llo, alo, palo);

    // ---- PV: V-frag read ONCE, 2 MFMAs ----
    #pragma unroll
    for (int dt = 0; dt < 4; ++dt)
      #pragma unroll
      for (int ks = 0; ks < 2; ++ks) {
        int row = dt * 16 + lr;
        bf16x8 vb = *(const bf16x8*)(smV[cur] + row * 128 +
                                     (((ks * 64) + 16 * lg) ^ ((row & 7) << 4)));
        union { unsigned int u[4]; bf16x8 v8; } ph, pl;
        ph.u[0] = pahi[ks][0]; ph.u[1] = pahi[ks][1];
        ph.u[2] = pahi[ks][2]; ph.u[3] = pahi[ks][3];
        ahi[dt] = __builtin_amdgcn_mfma_f32_16x16x32_bf16(ph.v8, vb, ahi[dt], 0, 0, 0);
        if (lo_act) {
          pl.u[0] = palo[ks][0]; pl.u[1] = palo[ks][1];
          pl.u[2] = palo[ks][2]; pl.u[3] = palo[ks][3];
          alo[dt] = __builtin_amdgcn_mfma_f32_16x16x32_bf16(pl.v8, vb, alo[dt], 0, 0, 0);
        }
      }

    if (kti + 1 < ntiles) write_lds(cur ^ 1);  // buf cur^1 free since barrier
    __syncthreads();
  }

  // ---- normalize and write out (bf16), both parts ----
  #pragma unroll
  for (int p = 0; p < 2; ++p) {
    const int q0 = p ? qhi0 : qlo0;
    const float inv = 1.0f / (p ? lhi : llo);
    float invO[4];
    #pragma unroll
    for (int r = 0; r < 4; ++r)
      invO[r] = __shfl(inv, (l & 48) | (lg * 4 + r));
    #pragma unroll
    for (int dt = 0; dt < 4; ++dt)
      #pragma unroll
      for (int r = 0; r < 4; ++r) {
        float vv = (p ? ahi : alo)[dt][r] * invO[r];
        attn_out[(size_t)(b * S_ + q0 + lg * 4 + r) * D_ + h * DH_ + dt * 16 + lr] = f2bf(vv);
      }
  }
}

extern "C" void kernel_launch(void* const* d_in, const int* in_sizes, int n_in,
                              void* d_out, int out_size, void* d_ws, size_t ws_size,
                              hipStream_t stream) {
  const float* x     = (const float*)d_in[0];
  const float* W_qkv = (const float*)d_in[1];
  const float* b_qkv = (const float*)d_in[2];
  const float* W_out = (const float*)d_in[3];
  const float* b_out = (const float*)d_in[4];
  float* out = (float*)d_out;

  char* ws = (char*)d_ws;
  unsigned short* qkv_bf  = (unsigned short*)ws;  ws += (size_t)M_ * QKV_LD * 2;
  unsigned short* attn_bf = (unsigned short*)ws;  ws += (size_t)M_ * D_ * 2;
  unsigned short* x_bf    = (unsigned short*)ws;  ws += (size_t)M_ * D_ * 2;
  unsigned short* wqkvT   = (unsigned short*)ws;  ws += (size_t)QKV_LD * D_ * 2;
  unsigned short* woutT   = (unsigned short*)ws;

  dim3 blk(256);
  // fused prep: conv (4096 blocks) + W_qkv^T (3072) + W_out^T (1024)
  prep_all<<<4096 + 3072 + 1024, blk, 0, stream>>>(x, x_bf, W_qkv, wqkvT, W_out, woutT);
  gemm_bf16_tn<unsigned short><<<dim3(QKV_LD / 128, M_ / 128), blk, 0, stream>>>(
      x_bf, wqkvT, b_qkv, qkv_bf, QKV_LD, D_);
  // 32 q-rows/wave balanced pairing + XCD-pinned bh (remap inside kernel)
  attn_fwd_mfma<<<dim3(512), dim3(256), 0, stream>>>(qkv_bf, attn_bf);
  gemm_bf16_tn<float><<<dim3(D_ / 128, M_ / 128), blk, 0, stream>>>(
      attn_bf, woutT, b_out, out, D_, D_);
}

// Round 18
// 119.365 us; speedup vs baseline: 1.1141x; 1.1141x over previous
//
#include <hip/hip_runtime.h>
#include <hip/hip_bf16.h>

#define B_  2
#define S_  2048
#define D_  1024
#define H_  16
#define DH_ 64
#define M_  (B_ * S_)       // 4096
#define QKV_LD (3 * D_)     // 3072

typedef __bf16 bf16x8 __attribute__((ext_vector_type(8)));
typedef float  f32x4  __attribute__((ext_vector_type(4)));
typedef unsigned short us4 __attribute__((ext_vector_type(4)));
typedef unsigned short us8 __attribute__((ext_vector_type(8)));

__device__ inline unsigned short f2bf(float f) {
  union { __bf16 h; unsigned short u; } cv; cv.h = (__bf16)f; return cv.u;
}
__device__ inline float bf2f(unsigned short u) {
  union { unsigned int i; float f; } cv; cv.i = ((unsigned int)u) << 16; return cv.f;
}
__device__ inline unsigned int pk2bf(float lo, float hi) {
  return (unsigned int)f2bf(lo) | ((unsigned int)f2bf(hi) << 16);
}
// typed stores: bf16 does the BIT conversion (round-3 bug: (unsigned short)v
// was an int conversion -> output was all-zero)
__device__ inline void cstore(float* p, float v) { *p = v; }
__device__ inline void cstore(unsigned short* p, float v) { *p = f2bf(v); }

__device__ inline void gload_lds16(const void* g, void* lds) {
  __builtin_amdgcn_global_load_lds(
      (const __attribute__((address_space(1))) unsigned int*)g,
      (__attribute__((address_space(3))) unsigned int*)lds, 16, 0, 0);
}

// ---------------- fused prep: x->bf16, W_qkv^T->bf16, W_out^T->bf16 ----------------
__global__ __launch_bounds__(256) void prep_all(
    const float* __restrict__ x, unsigned short* __restrict__ x_bf,
    const float* __restrict__ W_qkv, unsigned short* __restrict__ wqkvT,
    const float* __restrict__ W_out, unsigned short* __restrict__ woutT) {
  __shared__ float tile[32][33];
  const int blk = blockIdx.x;
  const int t = threadIdx.x;
  if (blk < 4096) {                       // conv x -> bf16, 4 floats/thread
    int i = blk * 256 + t;
    float4 v = ((const float4*)x)[i];
    us4 p = { f2bf(v.x), f2bf(v.y), f2bf(v.z), f2bf(v.w) };
    ((us4*)x_bf)[i] = p;
    return;
  }
  const float* W; unsigned short* Wt; int K, N, bi;
  if (blk < 4096 + 3072) { bi = blk - 4096; W = W_qkv; Wt = wqkvT; K = D_; N = QKV_LD; }
  else                   { bi = blk - 7168; W = W_out; Wt = woutT; K = D_; N = D_; }
  const int bx = bi % (N / 32), by = bi / (N / 32);
  const int tx = t & 31, ty = t >> 5;
  const int c0 = bx * 32, r0 = by * 32;
  #pragma unroll
  for (int i = 0; i < 4; ++i)
    tile[ty + 8 * i][tx] = W[(size_t)(r0 + ty + 8 * i) * N + c0 + tx];
  __syncthreads();
  #pragma unroll
  for (int i = 0; i < 4; ++i)
    Wt[(size_t)(c0 + ty + 8 * i) * K + r0 + tx] = f2bf(tile[tx][ty + 8 * i]);
}

// ---------------- bf16 MFMA GEMM (m97 structure + T1 XCD swizzle) ----------------
template<typename CT>
__global__ __launch_bounds__(256) void gemm_bf16_tn(
    const unsigned short* __restrict__ A,   // [M][K] bf16
    const unsigned short* __restrict__ Bt,  // [N][K] bf16
    const float* __restrict__ bias,
    CT* __restrict__ C, int N, int K) {
  __shared__ __align__(16) unsigned short smA[128 * 32];
  __shared__ __align__(16) unsigned short smB[128 * 32];
  const int t = threadIdx.x;
  const int w = t >> 6, l = t & 63;
  const int lg = l >> 4, lr = l & 15;
  // XCD swizzle (nwg % 8 == 0 for both GEMMs)
  const int nwg  = gridDim.x * gridDim.y;
  const int bid0 = blockIdx.y * gridDim.x + blockIdx.x;
  const int swz  = (bid0 & 7) * (nwg >> 3) + (bid0 >> 3);
  const int bx = swz % gridDim.x, by = swz / gridDim.x;
  const int row0 = by * 128, col0 = bx * 128;
  const int wm = (w >> 1) * 64, wn = (w & 1) * 64;

  f32x4 acc[4][4] = {};

  for (int k0 = 0; k0 < K; k0 += 32) {
    __syncthreads();  // previous iteration's fragment reads complete
    #pragma unroll
    for (int i = 0; i < 2; ++i) {
      const int inst = 2 * w + i;
      const int r = inst * 16 + (l >> 2);
      const int cb = (l & 3) * 8;  // k-chunk of 8 bf16
      gload_lds16(A  + (size_t)(row0 + r) * K + k0 + cb, &smA[inst * 512]);
      gload_lds16(Bt + (size_t)(col0 + r) * K + k0 + cb, &smB[inst * 512]);
    }
    __syncthreads();  // waits vmcnt(0): tiles resident

    bf16x8 af[4], bfr[4];
    #pragma unroll
    for (int m = 0; m < 4; ++m)
      af[m] = *(const bf16x8*)&smA[(wm + m * 16 + lr) * 32 + lg * 8];
    #pragma unroll
    for (int n = 0; n < 4; ++n)
      bfr[n] = *(const bf16x8*)&smB[(wn + n * 16 + lr) * 32 + lg * 8];
    #pragma unroll
    for (int m = 0; m < 4; ++m)
      #pragma unroll
      for (int n = 0; n < 4; ++n)
        acc[m][n] = __builtin_amdgcn_mfma_f32_16x16x32_bf16(af[m], bfr[n], acc[m][n], 0, 0, 0);
  }

  #pragma unroll
  for (int m = 0; m < 4; ++m) {
    #pragma unroll
    for (int n = 0; n < 4; ++n) {
      const int col = col0 + wn + n * 16 + lr;
      const float bv = bias[col];
      #pragma unroll
      for (int r = 0; r < 4; ++r) {
        const int row = row0 + wm + m * 16 + lg * 4 + r;
        cstore(&C[(size_t)row * N + col], acc[m][n][r] + bv);
      }
    }
  }
}

// ---------------- Causal flash attention, bf16 MFMA ----------------
// Round-13 structure (best: 53.4 us): 512 blocks x 512 threads (8 waves),
// waves 0-3 own q-tile lo=x, waves 4-7 own hi=31-x, one k-loop of 32-x
// tiles (lo active while kti <= x). K/V staged once/tile by threads <256.
// XCD-pinned bh; sigma-permuted K rows (PV A-frag packs in-lane); log2
// softmax + defer-max; LDS dbuf; 1 barrier/tile.
// r18 change: ZERO cross-lane ops in the common softmax path --
//  (a) defer-max test uses the IN-LANE max only (equally conservative);
//      the xor16/32 max reduce moved inside the rare rescale branch;
//  (b) lrun kept as per-lane PARTIAL sum (alpha is row-uniform), reduced
//      once after the k-loop.  [was: 4 shfl_xor per tile on the chain]
// [r14: intra-wave T15 pipelining regressed; r16: KVBLK=128 regressed
//  (V-row ks-bit XOR collision); r17: 32 rows/wave at 4 waves regressed
//  (TLP loss beats LDS-traffic halving -- kernel is latency-bound).]
// sigma(rho) = 32*(rho>>5)+8*((rho>>2)&3)+4*((rho>>4)&1)+(rho&3).
__global__ __launch_bounds__(512, 4) void attn_fwd_mfma(
    const unsigned short* __restrict__ qkv, unsigned short* __restrict__ attn_out) {
  const int bid = blockIdx.x;           // 0..511
  const int xcd = bid & 7;
  const int li  = bid >> 3;             // 0..63 within XCD
  const int bh  = xcd * 4 + (li >> 4);  // 4 bh per XCD
  const int x   = li & 15;              // pair index: lo q-tile x, hi 31-x
  const int b = bh / H_, h = bh % H_;
  const unsigned short* base = qkv + (size_t)b * S_ * QKV_LD;

  __shared__ __align__(16) char smK[2][64 * 128];  // K tile [sigma-row][d], XOR-swizzled
  __shared__ __align__(16) char smV[2][64 * 128];  // V^T tile [d][k]

  const int t  = threadIdx.x;           // 0..511
  const int w  = t >> 6;                // 0..7
  const bool lo = (w < 4);
  const int wq = w & 3;
  const int l  = t & 63;
  const int lg = l >> 4;
  const int lr = l & 15;

  const int qt  = lo ? x : (31 - x);
  const int qw0 = qt * 64 + wq * 16;    // wave owns rows qw0..qw0+15

  const unsigned short* kbase = base + D_ + h * DH_;
  const unsigned short* vbase = base + 2 * D_ + h * DH_;

  // staging (threads <256 only): T14 async split, issue early / write late
  us8 kreg[2], vreg[2];
  const int kp  = (t & 31) * 2;          // V: pair of k-columns
  const int vdb = ((t >> 5) & 7) * 8;    // V: 8 d-rows

  auto issue_loads = [&](int k0) {
    #pragma unroll
    for (int it = 0; it < 2; ++it) {
      int idx = t + it * 256;
      int r = idx >> 3, c = idx & 7;
      kreg[it] = *(const us8*)(kbase + (size_t)(k0 + r) * QKV_LD + c * 8);
    }
    vreg[0] = *(const us8*)(vbase + (size_t)(k0 + kp) * QKV_LD + vdb);
    vreg[1] = *(const us8*)(vbase + (size_t)(k0 + kp + 1) * QKV_LD + vdb);
  };
  auto write_lds = [&](int buf) {
    #pragma unroll
    for (int it = 0; it < 2; ++it) {
      int idx = t + it * 256;
      int r = idx >> 3, c = idx & 7;
      // sigma^-1: global k-row r -> LDS row rho (pure bit permutation)
      int rho = (r & 0x23) | ((r & 0x04) << 2) | ((r & 0x18) >> 1);
      *(us8*)(smK[buf] + rho * 128 + ((c * 16) ^ ((rho & 7) << 4))) = kreg[it];
    }
    #pragma unroll
    for (int j = 0; j < 8; ++j) {
      int row = vdb + j;
      unsigned int pv = (unsigned int)vreg[0][j] | ((unsigned int)vreg[1][j] << 16);
      *(unsigned int*)(smV[buf] + row * 128 + ((2 * kp) ^ ((row & 7) << 4))) = pv;
    }
  };

  // ---- Q fragments (scale = 1/8 * log2(e): softmax in log2 domain) ----
  bf16x8 qf[2];
  {
    const unsigned short* qp = base + (size_t)(qw0 + lr) * QKV_LD + h * DH_ + 8 * lg;
    #pragma unroll
    for (int ks = 0; ks < 2; ++ks) {
      us8 qv = *(const us8*)(qp + 32 * ks);
      #pragma unroll
      for (int e = 0; e < 8; ++e) qf[ks][e] = (__bf16)(bf2f(qv[e]) * 0.18033688f);
    }
  }

  float mrun = -1e30f, lrun = 0.f;   // lrun = per-lane PARTIAL sum (r18)
  f32x4 acc_o[4] = {};

  const int ntiles = 32 - x;   // hi's tile count (superset of lo's x+1)
  if (t < 256) { issue_loads(0); write_lds(0); }
  __syncthreads();

  for (int kti = 0; kti < ntiles; ++kti) {
    const int k0 = kti * 64;
    const int cur = kti & 1;

    if (t < 256 && kti + 1 < ntiles) issue_loads((kti + 1) * 64);

    const bool active = lo ? (kti <= x) : true;   // wave-uniform
    if (active) {
      // ---- swapped QK^T on sigma-permuted K rows ----
      f32x4 sc[4] = {};
      #pragma unroll
      for (int kt = 0; kt < 4; ++kt)
        #pragma unroll
        for (int ks = 0; ks < 2; ++ks) {
          int row = kt * 16 + lr;
          bf16x8 kb_ = *(const bf16x8*)(smK[cur] + row * 128 +
                                        (((ks * 64) + 16 * lg) ^ ((row & 7) << 4)));
          sc[kt] = __builtin_amdgcn_mfma_f32_16x16x32_bf16(kb_, qf[ks], sc[kt], 0, 0, 0);
        }

      // ---- causal mask: sc[kt][r] true k = k0+32*(kt>>1)+8*lg+4*(kt&1)+r ----
      if (k0 + 63 > qw0) {
        #pragma unroll
        for (int kt = 0; kt < 4; ++kt)
          #pragma unroll
          for (int r = 0; r < 4; ++r) {
            int kc = k0 + ((kt >> 1) << 5) + (lg << 3) + ((kt & 1) << 2) + r;
            if (kc > qw0 + lr) sc[kt][r] = -1e30f;
          }
      }

      // ---- online softmax (log2 domain), zero cross-lane common path ----
      float v = fmaxf(fmaxf(sc[0][0], sc[0][1]), fmaxf(sc[0][2], sc[0][3]));
      #pragma unroll
      for (int kt = 1; kt < 4; ++kt)
        v = fmaxf(v, fmaxf(fmaxf(sc[kt][0], sc[kt][1]), fmaxf(sc[kt][2], sc[kt][3])));
      // defer-max on the IN-LANE max: if every lane's local max is within
      // threshold, the row max is too (equally conservative, no shfl).
      if (!__all(v <= mrun + 8.0f)) {
        v = fmaxf(v, __shfl_xor(v, 16));       // full row reduce (rare path)
        v = fmaxf(v, __shfl_xor(v, 32));
        const float mnew = fmaxf(mrun, v);
        const float alpha = exp2f(mrun - mnew);  // row-uniform
        mrun = mnew;
        float alphaO[4];
        #pragma unroll
        for (int r = 0; r < 4; ++r)
          alphaO[r] = __shfl(alpha, (l & 48) | (lg * 4 + r));
        #pragma unroll
        for (int dt = 0; dt < 4; ++dt)
          #pragma unroll
          for (int r = 0; r < 4; ++r) acc_o[dt][r] *= alphaO[r];
        lrun *= alpha;                           // partial sum scales uniformly
      }
      float s = 0.f;
      #pragma unroll
      for (int kt = 0; kt < 4; ++kt)
        #pragma unroll
        for (int r = 0; r < 4; ++r) {
          float p = exp2f(sc[kt][r] - mrun);
          sc[kt][r] = p;
          s += p;
        }
      lrun += s;                                 // no per-tile reduce (r18)

      // ---- PV A-fragments: pure in-lane pack (sigma made slots line up) ----
      union { unsigned int u[4]; bf16x8 v8; } pa[2];
      #pragma unroll
      for (int ks = 0; ks < 2; ++ks) {
        pa[ks].u[0] = pk2bf(sc[2 * ks][0], sc[2 * ks][1]);
        pa[ks].u[1] = pk2bf(sc[2 * ks][2], sc[2 * ks][3]);
        pa[ks].u[2] = pk2bf(sc[2 * ks + 1][0], sc[2 * ks + 1][1]);
        pa[ks].u[3] = pk2bf(sc[2 * ks + 1][2], sc[2 * ks + 1][3]);
      }

      // ---- PV ----
      #pragma unroll
      for (int dt = 0; dt < 4; ++dt)
        #pragma unroll
        for (int ks = 0; ks < 2; ++ks) {
          int row = dt * 16 + lr;
          bf16x8 vb = *(const bf16x8*)(smV[cur] + row * 128 +
                                       (((ks * 64) + 16 * lg) ^ ((row & 7) << 4)));
          acc_o[dt] = __builtin_amdgcn_mfma_f32_16x16x32_bf16(pa[ks].v8, vb, acc_o[dt], 0, 0, 0);
        }
    }

    if (t < 256 && kti + 1 < ntiles) write_lds(cur ^ 1);  // buf cur^1 free since barrier
    __syncthreads();
  }

  // ---- final row-sum reduce (once), normalize, write out (bf16) ----
  float ltot = lrun;
  ltot += __shfl_xor(ltot, 16);
  ltot += __shfl_xor(ltot, 32);
  const float inv = 1.0f / ltot;   // for q-row qw0+lr
  float invO[4];
  #pragma unroll
  for (int r = 0; r < 4; ++r)
    invO[r] = __shfl(inv, (l & 48) | (lg * 4 + r));
  #pragma unroll
  for (int dt = 0; dt < 4; ++dt)
    #pragma unroll
    for (int r = 0; r < 4; ++r)
      attn_out[(size_t)(b * S_ + qw0 + lg * 4 + r) * D_ + h * DH_ + dt * 16 + lr] =
          f2bf(acc_o[dt][r] * invO[r]);
}

extern "C" void kernel_launch(void* const* d_in, const int* in_sizes, int n_in,
                              void* d_out, int out_size, void* d_ws, size_t ws_size,
                              hipStream_t stream) {
  const float* x     = (const float*)d_in[0];
  const float* W_qkv = (const float*)d_in[1];
  const float* b_qkv = (const float*)d_in[2];
  const float* W_out = (const float*)d_in[3];
  const float* b_out = (const float*)d_in[4];
  float* out = (float*)d_out;

  char* ws = (char*)d_ws;
  unsigned short* qkv_bf  = (unsigned short*)ws;  ws += (size_t)M_ * QKV_LD * 2;
  unsigned short* attn_bf = (unsigned short*)ws;  ws += (size_t)M_ * D_ * 2;
  unsigned short* x_bf    = (unsigned short*)ws;  ws += (size_t)M_ * D_ * 2;
  unsigned short* wqkvT   = (unsigned short*)ws;  ws += (size_t)QKV_LD * D_ * 2;
  unsigned short* woutT   = (unsigned short*)ws;

  dim3 blk(256);
  // fused prep: conv (4096 blocks) + W_qkv^T (3072) + W_out^T (1024)
  prep_all<<<4096 + 3072 + 1024, blk, 0, stream>>>(x, x_bf, W_qkv, wqkvT, W_out, woutT);
  gemm_bf16_tn<unsigned short><<<dim3(QKV_LD / 128, M_ / 128), blk, 0, stream>>>(
      x_bf, wqkvT, b_qkv, qkv_bf, QKV_LD, D_);
  // lo/hi wave-split balanced pairing + XCD-pinned bh (r13 structure)
  attn_fwd_mfma<<<dim3(512), dim3(512), 0, stream>>>(qkv_bf, attn_bf);
  gemm_bf16_tn<float><<<dim3(D_ / 128, M_ / 128), blk, 0, stream>>>(
      attn_bf, woutT, b_out, out, D_, D_);
}

// Round 19
// 116.147 us; speedup vs baseline: 1.1450x; 1.0277x over previous
//
#include <hip/hip_runtime.h>
#include <hip/hip_bf16.h>

#define B_  2
#define S_  2048
#define D_  1024
#define H_  16
#define DH_ 64
#define M_  (B_ * S_)       // 4096
#define QKV_LD (3 * D_)     // 3072

typedef __bf16 bf16x8 __attribute__((ext_vector_type(8)));
typedef float  f32x4  __attribute__((ext_vector_type(4)));
typedef unsigned short us4 __attribute__((ext_vector_type(4)));
typedef unsigned short us8 __attribute__((ext_vector_type(8)));

__device__ inline unsigned short f2bf(float f) {
  union { __bf16 h; unsigned short u; } cv; cv.h = (__bf16)f; return cv.u;
}
__device__ inline float bf2f(unsigned short u) {
  union { unsigned int i; float f; } cv; cv.i = ((unsigned int)u) << 16; return cv.f;
}
__device__ inline unsigned int pk2bf(float lo, float hi) {
  return (unsigned int)f2bf(lo) | ((unsigned int)f2bf(hi) << 16);
}
// typed stores: bf16 does the BIT conversion (round-3 bug: (unsigned short)v
// was an int conversion -> output was all-zero)
__device__ inline void cstore(float* p, float v) { *p = v; }
__device__ inline void cstore(unsigned short* p, float v) { *p = f2bf(v); }

__device__ inline void gload_lds16(const void* g, void* lds) {
  __builtin_amdgcn_global_load_lds(
      (const __attribute__((address_space(1))) unsigned int*)g,
      (__attribute__((address_space(3))) unsigned int*)lds, 16, 0, 0);
}

// ---------------- fused prep: x->bf16, W_qkv^T->bf16, W_out^T->bf16 ----------------
__global__ __launch_bounds__(256) void prep_all(
    const float* __restrict__ x, unsigned short* __restrict__ x_bf,
    const float* __restrict__ W_qkv, unsigned short* __restrict__ wqkvT,
    const float* __restrict__ W_out, unsigned short* __restrict__ woutT) {
  __shared__ float tile[32][33];
  const int blk = blockIdx.x;
  const int t = threadIdx.x;
  if (blk < 4096) {                       // conv x -> bf16, 4 floats/thread
    int i = blk * 256 + t;
    float4 v = ((const float4*)x)[i];
    us4 p = { f2bf(v.x), f2bf(v.y), f2bf(v.z), f2bf(v.w) };
    ((us4*)x_bf)[i] = p;
    return;
  }
  const float* W; unsigned short* Wt; int K, N, bi;
  if (blk < 4096 + 3072) { bi = blk - 4096; W = W_qkv; Wt = wqkvT; K = D_; N = QKV_LD; }
  else                   { bi = blk - 7168; W = W_out; Wt = woutT; K = D_; N = D_; }
  const int bx = bi % (N / 32), by = bi / (N / 32);
  const int tx = t & 31, ty = t >> 5;
  const int c0 = bx * 32, r0 = by * 32;
  #pragma unroll
  for (int i = 0; i < 4; ++i)
    tile[ty + 8 * i][tx] = W[(size_t)(r0 + ty + 8 * i) * N + c0 + tx];
  __syncthreads();
  #pragma unroll
  for (int i = 0; i < 4; ++i)
    Wt[(size_t)(c0 + ty + 8 * i) * K + r0 + tx] = f2bf(tile[tx][ty + 8 * i]);
}

// ---------------- bf16 MFMA GEMM (m97 structure + T1 XCD swizzle) ----------------
// C[M,N] = A[M,K] @ Bt[N,K]^T + bias.  BM=128 x BN tile, BK=32, 4 waves
// (2x2); BN=128 -> 32 MFMA/wave/k-step, BN=64 -> 16 (half B staging, 2x
// grid -- r19: fixes out-proj's 1-block/CU grid starvation).
template<int BN, typename CT>
__global__ __launch_bounds__(256) void gemm_bf16_tn(
    const unsigned short* __restrict__ A,   // [M][K] bf16
    const unsigned short* __restrict__ Bt,  // [N][K] bf16
    const float* __restrict__ bias,
    CT* __restrict__ C, int N, int K) {
  constexpr int NFR = BN / 32;            // B-frags per wave (128->4, 64->2)
  constexpr int NBI = BN / 64;            // B staging insts per wave
  __shared__ __align__(16) unsigned short smA[128 * 32];
  __shared__ __align__(16) unsigned short smB[BN * 32];
  const int t = threadIdx.x;
  const int w = t >> 6, l = t & 63;
  const int lg = l >> 4, lr = l & 15;
  // XCD swizzle (nwg % 8 == 0 for all uses)
  const int nwg  = gridDim.x * gridDim.y;
  const int bid0 = blockIdx.y * gridDim.x + blockIdx.x;
  const int swz  = (bid0 & 7) * (nwg >> 3) + (bid0 >> 3);
  const int bx = swz % gridDim.x, by = swz / gridDim.x;
  const int row0 = by * 128, col0 = bx * BN;
  const int wm = (w >> 1) * 64, wn = (w & 1) * (BN / 2);

  f32x4 acc[4][NFR] = {};

  for (int k0 = 0; k0 < K; k0 += 32) {
    __syncthreads();  // previous iteration's fragment reads complete
    #pragma unroll
    for (int i = 0; i < 2; ++i) {   // A: 8 insts, 2/wave
      const int inst = 2 * w + i;
      const int r = inst * 16 + (l >> 2);
      const int cb = (l & 3) * 8;
      gload_lds16(A + (size_t)(row0 + r) * K + k0 + cb, &smA[inst * 512]);
    }
    #pragma unroll
    for (int i = 0; i < NBI; ++i) { // B: BN/16 insts, NBI/wave
      const int inst = NBI * w + i;
      const int r = inst * 16 + (l >> 2);
      const int cb = (l & 3) * 8;
      gload_lds16(Bt + (size_t)(col0 + r) * K + k0 + cb, &smB[inst * 512]);
    }
    __syncthreads();  // waits vmcnt(0): tiles resident

    bf16x8 af[4], bfr[NFR];
    #pragma unroll
    for (int m = 0; m < 4; ++m)
      af[m] = *(const bf16x8*)&smA[(wm + m * 16 + lr) * 32 + lg * 8];
    #pragma unroll
    for (int n = 0; n < NFR; ++n)
      bfr[n] = *(const bf16x8*)&smB[(wn + n * 16 + lr) * 32 + lg * 8];
    #pragma unroll
    for (int m = 0; m < 4; ++m)
      #pragma unroll
      for (int n = 0; n < NFR; ++n)
        acc[m][n] = __builtin_amdgcn_mfma_f32_16x16x32_bf16(af[m], bfr[n], acc[m][n], 0, 0, 0);
  }

  #pragma unroll
  for (int m = 0; m < 4; ++m) {
    #pragma unroll
    for (int n = 0; n < NFR; ++n) {
      const int col = col0 + wn + n * 16 + lr;
      const float bv = bias[col];
      #pragma unroll
      for (int r = 0; r < 4; ++r) {
        const int row = row0 + wm + m * 16 + lg * 4 + r;
        cstore(&C[(size_t)row * N + col], acc[m][n][r] + bv);
      }
    }
  }
}

// ---------------- Causal flash attention, bf16 MFMA ----------------
// r18 kernel verbatim (best: ~50 us). 512 blocks x 512 threads (8 waves),
// waves 0-3 own q-tile lo=x, waves 4-7 own hi=31-x, one k-loop of 32-x
// tiles (lo active while kti <= x). K/V staged once/tile by threads <256.
// XCD-pinned bh; sigma-permuted K rows (PV A-frag packs in-lane); log2
// softmax + defer-max; zero cross-lane common path (in-lane defer test,
// per-lane partial sum reduced once at end); LDS dbuf; 1 barrier/tile.
// [r14: intra-wave T15 regressed; r16: KVBLK=128 regressed; r17: 32
//  rows/wave at 4 waves regressed -- kernel is latency-bound.]
// sigma(rho) = 32*(rho>>5)+8*((rho>>2)&3)+4*((rho>>4)&1)+(rho&3).
__global__ __launch_bounds__(512, 4) void attn_fwd_mfma(
    const unsigned short* __restrict__ qkv, unsigned short* __restrict__ attn_out) {
  const int bid = blockIdx.x;           // 0..511
  const int xcd = bid & 7;
  const int li  = bid >> 3;             // 0..63 within XCD
  const int bh  = xcd * 4 + (li >> 4);  // 4 bh per XCD
  const int x   = li & 15;              // pair index: lo q-tile x, hi 31-x
  const int b = bh / H_, h = bh % H_;
  const unsigned short* base = qkv + (size_t)b * S_ * QKV_LD;

  __shared__ __align__(16) char smK[2][64 * 128];  // K tile [sigma-row][d], XOR-swizzled
  __shared__ __align__(16) char smV[2][64 * 128];  // V^T tile [d][k]

  const int t  = threadIdx.x;           // 0..511
  const int w  = t >> 6;                // 0..7
  const bool lo = (w < 4);
  const int wq = w & 3;
  const int l  = t & 63;
  const int lg = l >> 4;
  const int lr = l & 15;

  const int qt  = lo ? x : (31 - x);
  const int qw0 = qt * 64 + wq * 16;    // wave owns rows qw0..qw0+15

  const unsigned short* kbase = base + D_ + h * DH_;
  const unsigned short* vbase = base + 2 * D_ + h * DH_;

  // staging (threads <256 only): T14 async split, issue early / write late
  us8 kreg[2], vreg[2];
  const int kp  = (t & 31) * 2;          // V: pair of k-columns
  const int vdb = ((t >> 5) & 7) * 8;    // V: 8 d-rows

  auto issue_loads = [&](int k0) {
    #pragma unroll
    for (int it = 0; it < 2; ++it) {
      int idx = t + it * 256;
      int r = idx >> 3, c = idx & 7;
      kreg[it] = *(const us8*)(kbase + (size_t)(k0 + r) * QKV_LD + c * 8);
    }
    vreg[0] = *(const us8*)(vbase + (size_t)(k0 + kp) * QKV_LD + vdb);
    vreg[1] = *(const us8*)(vbase + (size_t)(k0 + kp + 1) * QKV_LD + vdb);
  };
  auto write_lds = [&](int buf) {
    #pragma unroll
    for (int it = 0; it < 2; ++it) {
      int idx = t + it * 256;
      int r = idx >> 3, c = idx & 7;
      // sigma^-1: global k-row r -> LDS row rho (pure bit permutation)
      int rho = (r & 0x23) | ((r & 0x04) << 2) | ((r & 0x18) >> 1);
      *(us8*)(smK[buf] + rho * 128 + ((c * 16) ^ ((rho & 7) << 4))) = kreg[it];
    }
    #pragma unroll
    for (int j = 0; j < 8; ++j) {
      int row = vdb + j;
      unsigned int pv = (unsigned int)vreg[0][j] | ((unsigned int)vreg[1][j] << 16);
      *(unsigned int*)(smV[buf] + row * 128 + ((2 * kp) ^ ((row & 7) << 4))) = pv;
    }
  };

  // ---- Q fragments (scale = 1/8 * log2(e): softmax in log2 domain) ----
  bf16x8 qf[2];
  {
    const unsigned short* qp = base + (size_t)(qw0 + lr) * QKV_LD + h * DH_ + 8 * lg;
    #pragma unroll
    for (int ks = 0; ks < 2; ++ks) {
      us8 qv = *(const us8*)(qp + 32 * ks);
      #pragma unroll
      for (int e = 0; e < 8; ++e) qf[ks][e] = (__bf16)(bf2f(qv[e]) * 0.18033688f);
    }
  }

  float mrun = -1e30f, lrun = 0.f;   // lrun = per-lane PARTIAL sum (r18)
  f32x4 acc_o[4] = {};

  const int ntiles = 32 - x;   // hi's tile count (superset of lo's x+1)
  if (t < 256) { issue_loads(0); write_lds(0); }
  __syncthreads();

  for (int kti = 0; kti < ntiles; ++kti) {
    const int k0 = kti * 64;
    const int cur = kti & 1;

    if (t < 256 && kti + 1 < ntiles) issue_loads((kti + 1) * 64);

    const bool active = lo ? (kti <= x) : true;   // wave-uniform
    if (active) {
      // ---- swapped QK^T on sigma-permuted K rows ----
      f32x4 sc[4] = {};
      #pragma unroll
      for (int kt = 0; kt < 4; ++kt)
        #pragma unroll
        for (int ks = 0; ks < 2; ++ks) {
          int row = kt * 16 + lr;
          bf16x8 kb_ = *(const bf16x8*)(smK[cur] + row * 128 +
                                        (((ks * 64) + 16 * lg) ^ ((row & 7) << 4)));
          sc[kt] = __builtin_amdgcn_mfma_f32_16x16x32_bf16(kb_, qf[ks], sc[kt], 0, 0, 0);
        }

      // ---- causal mask: sc[kt][r] true k = k0+32*(kt>>1)+8*lg+4*(kt&1)+r ----
      if (k0 + 63 > qw0) {
        #pragma unroll
        for (int kt = 0; kt < 4; ++kt)
          #pragma unroll
          for (int r = 0; r < 4; ++r) {
            int kc = k0 + ((kt >> 1) << 5) + (lg << 3) + ((kt & 1) << 2) + r;
            if (kc > qw0 + lr) sc[kt][r] = -1e30f;
          }
      }

      // ---- online softmax (log2 domain), zero cross-lane common path ----
      float v = fmaxf(fmaxf(sc[0][0], sc[0][1]), fmaxf(sc[0][2], sc[0][3]));
      #pragma unroll
      for (int kt = 1; kt < 4; ++kt)
        v = fmaxf(v, fmaxf(fmaxf(sc[kt][0], sc[kt][1]), fmaxf(sc[kt][2], sc[kt][3])));
      // defer-max on the IN-LANE max: if every lane's local max is within
      // threshold, the row max is too (equally conservative, no shfl).
      if (!__all(v <= mrun + 8.0f)) {
        v = fmaxf(v, __shfl_xor(v, 16));       // full row reduce (rare path)
        v = fmaxf(v, __shfl_xor(v, 32));
        const float mnew = fmaxf(mrun, v);
        const float alpha = exp2f(mrun - mnew);  // row-uniform
        mrun = mnew;
        float alphaO[4];
        #pragma unroll
        for (int r = 0; r < 4; ++r)
          alphaO[r] = __shfl(alpha, (l & 48) | (lg * 4 + r));
        #pragma unroll
        for (int dt = 0; dt < 4; ++dt)
          #pragma unroll
          for (int r = 0; r < 4; ++r) acc_o[dt][r] *= alphaO[r];
        lrun *= alpha;                           // partial sum scales uniformly
      }
      float s = 0.f;
      #pragma unroll
      for (int kt = 0; kt < 4; ++kt)
        #pragma unroll
        for (int r = 0; r < 4; ++r) {
          float p = exp2f(sc[kt][r] - mrun);
          sc[kt][r] = p;
          s += p;
        }
      lrun += s;                                 // no per-tile reduce (r18)

      // ---- PV A-fragments: pure in-lane pack (sigma made slots line up) ----
      union { unsigned int u[4]; bf16x8 v8; } pa[2];
      #pragma unroll
      for (int ks = 0; ks < 2; ++ks) {
        pa[ks].u[0] = pk2bf(sc[2 * ks][0], sc[2 * ks][1]);
        pa[ks].u[1] = pk2bf(sc[2 * ks][2], sc[2 * ks][3]);
        pa[ks].u[2] = pk2bf(sc[2 * ks + 1][0], sc[2 * ks + 1][1]);
        pa[ks].u[3] = pk2bf(sc[2 * ks + 1][2], sc[2 * ks + 1][3]);
      }

      // ---- PV ----
      #pragma unroll
      for (int dt = 0; dt < 4; ++dt)
        #pragma unroll
        for (int ks = 0; ks < 2; ++ks) {
          int row = dt * 16 + lr;
          bf16x8 vb = *(const bf16x8*)(smV[cur] + row * 128 +
                                       (((ks * 64) + 16 * lg) ^ ((row & 7) << 4)));
          acc_o[dt] = __builtin_amdgcn_mfma_f32_16x16x32_bf16(pa[ks].v8, vb, acc_o[dt], 0, 0, 0);
        }
    }

    if (t < 256 && kti + 1 < ntiles) write_lds(cur ^ 1);  // buf cur^1 free since barrier
    __syncthreads();
  }

  // ---- final row-sum reduce (once), normalize, write out (bf16) ----
  float ltot = lrun;
  ltot += __shfl_xor(ltot, 16);
  ltot += __shfl_xor(ltot, 32);
  const float inv = 1.0f / ltot;   // for q-row qw0+lr
  float invO[4];
  #pragma unroll
  for (int r = 0; r < 4; ++r)
    invO[r] = __shfl(inv, (l & 48) | (lg * 4 + r));
  #pragma unroll
  for (int dt = 0; dt < 4; ++dt)
    #pragma unroll
    for (int r = 0; r < 4; ++r)
      attn_out[(size_t)(b * S_ + qw0 + lg * 4 + r) * D_ + h * DH_ + dt * 16 + lr] =
          f2bf(acc_o[dt][r] * invO[r]);
}

extern "C" void kernel_launch(void* const* d_in, const int* in_sizes, int n_in,
                              void* d_out, int out_size, void* d_ws, size_t ws_size,
                              hipStream_t stream) {
  const float* x     = (const float*)d_in[0];
  const float* W_qkv = (const float*)d_in[1];
  const float* b_qkv = (const float*)d_in[2];
  const float* W_out = (const float*)d_in[3];
  const float* b_out = (const float*)d_in[4];
  float* out = (float*)d_out;

  char* ws = (char*)d_ws;
  unsigned short* qkv_bf  = (unsigned short*)ws;  ws += (size_t)M_ * QKV_LD * 2;
  unsigned short* attn_bf = (unsigned short*)ws;  ws += (size_t)M_ * D_ * 2;
  unsigned short* x_bf    = (unsigned short*)ws;  ws += (size_t)M_ * D_ * 2;
  unsigned short* wqkvT   = (unsigned short*)ws;  ws += (size_t)QKV_LD * D_ * 2;
  unsigned short* woutT   = (unsigned short*)ws;

  dim3 blk(256);
  // fused prep: conv (4096 blocks) + W_qkv^T (3072) + W_out^T (1024)
  prep_all<<<4096 + 3072 + 1024, blk, 0, stream>>>(x, x_bf, W_qkv, wqkvT, W_out, woutT);
  // QKV: 128x128 tile, grid (24,32)=768 blocks (3/CU)
  gemm_bf16_tn<128, unsigned short><<<dim3(QKV_LD / 128, M_ / 128), blk, 0, stream>>>(
      x_bf, wqkvT, b_qkv, qkv_bf, QKV_LD, D_);
  // lo/hi wave-split balanced pairing + XCD-pinned bh (r18 kernel)
  attn_fwd_mfma<<<dim3(512), dim3(512), 0, stream>>>(qkv_bf, attn_bf);
  // out-proj: 128x64 tile, grid (16,32)=512 blocks (2/CU; was 256=1/CU)
  gemm_bf16_tn<64, float><<<dim3(D_ / 64, M_ / 128), blk, 0, stream>>>(
      attn_bf, woutT, b_out, out, D_, D_);
}

// Round 20
// 115.666 us; speedup vs baseline: 1.1498x; 1.0042x over previous
//
#include <hip/hip_runtime.h>
#include <hip/hip_bf16.h>

#define B_  2
#define S_  2048
#define D_  1024
#define H_  16
#define DH_ 64
#define M_  (B_ * S_)       // 4096
#define QKV_LD (3 * D_)     // 3072

typedef __bf16 bf16x8 __attribute__((ext_vector_type(8)));
typedef float  f32x4  __attribute__((ext_vector_type(4)));
typedef unsigned short us4 __attribute__((ext_vector_type(4)));
typedef unsigned short us8 __attribute__((ext_vector_type(8)));

__device__ inline unsigned short f2bf(float f) {
  union { __bf16 h; unsigned short u; } cv; cv.h = (__bf16)f; return cv.u;
}
__device__ inline float bf2f(unsigned short u) {
  union { unsigned int i; float f; } cv; cv.i = ((unsigned int)u) << 16; return cv.f;
}
__device__ inline unsigned int pk2bf(float lo, float hi) {
  return (unsigned int)f2bf(lo) | ((unsigned int)f2bf(hi) << 16);
}
// typed stores: bf16 does the BIT conversion (round-3 bug: (unsigned short)v
// was an int conversion -> output was all-zero)
__device__ inline void cstore(float* p, float v) { *p = v; }
__device__ inline void cstore(unsigned short* p, float v) { *p = f2bf(v); }

__device__ inline void gload_lds16(const void* g, void* lds) {
  __builtin_amdgcn_global_load_lds(
      (const __attribute__((address_space(1))) unsigned int*)g,
      (__attribute__((address_space(3))) unsigned int*)lds, 16, 0, 0);
}

// ---------------- fused prep: x->bf16, W_qkv^T->bf16, W_out^T->bf16 ----------------
__global__ __launch_bounds__(256) void prep_all(
    const float* __restrict__ x, unsigned short* __restrict__ x_bf,
    const float* __restrict__ W_qkv, unsigned short* __restrict__ wqkvT,
    const float* __restrict__ W_out, unsigned short* __restrict__ woutT) {
  __shared__ float tile[32][33];
  const int blk = blockIdx.x;
  const int t = threadIdx.x;
  if (blk < 4096) {                       // conv x -> bf16, 4 floats/thread
    int i = blk * 256 + t;
    float4 v = ((const float4*)x)[i];
    us4 p = { f2bf(v.x), f2bf(v.y), f2bf(v.z), f2bf(v.w) };
    ((us4*)x_bf)[i] = p;
    return;
  }
  const float* W; unsigned short* Wt; int K, N, bi;
  if (blk < 4096 + 3072) { bi = blk - 4096; W = W_qkv; Wt = wqkvT; K = D_; N = QKV_LD; }
  else                   { bi = blk - 7168; W = W_out; Wt = woutT; K = D_; N = D_; }
  const int bx = bi % (N / 32), by = bi / (N / 32);
  const int tx = t & 31, ty = t >> 5;
  const int c0 = bx * 32, r0 = by * 32;
  #pragma unroll
  for (int i = 0; i < 4; ++i)
    tile[ty + 8 * i][tx] = W[(size_t)(r0 + ty + 8 * i) * N + c0 + tx];
  __syncthreads();
  #pragma unroll
  for (int i = 0; i < 4; ++i)
    Wt[(size_t)(c0 + ty + 8 * i) * K + r0 + tx] = f2bf(tile[tx][ty + 8 * i]);
}

// ---------------- bf16 MFMA GEMM (m97 structure + T1 XCD swizzle) ----------------
// C[M,N] = A[M,K] @ Bt[N,K]^T + bias.  BM=128 x BN tile, BK=32, 4 waves
// (2x2); BN=128 -> 32 MFMA/wave/k-step, BN=64 -> 16 (half B staging, 2x
// grid -- r19: fixed out-proj's 1-block/CU grid starvation, -4.6 us).
template<int BN, typename CT>
__global__ __launch_bounds__(256) void gemm_bf16_tn(
    const unsigned short* __restrict__ A,   // [M][K] bf16
    const unsigned short* __restrict__ Bt,  // [N][K] bf16
    const float* __restrict__ bias,
    CT* __restrict__ C, int N, int K) {
  constexpr int NFR = BN / 32;            // B-frags per wave (128->4, 64->2)
  constexpr int NBI = BN / 64;            // B staging insts per wave
  __shared__ __align__(16) unsigned short smA[128 * 32];
  __shared__ __align__(16) unsigned short smB[BN * 32];
  const int t = threadIdx.x;
  const int w = t >> 6, l = t & 63;
  const int lg = l >> 4, lr = l & 15;
  // XCD swizzle (nwg % 8 == 0 for all uses)
  const int nwg  = gridDim.x * gridDim.y;
  const int bid0 = blockIdx.y * gridDim.x + blockIdx.x;
  const int swz  = (bid0 & 7) * (nwg >> 3) + (bid0 >> 3);
  const int bx = swz % gridDim.x, by = swz / gridDim.x;
  const int row0 = by * 128, col0 = bx * BN;
  const int wm = (w >> 1) * 64, wn = (w & 1) * (BN / 2);

  f32x4 acc[4][NFR] = {};

  for (int k0 = 0; k0 < K; k0 += 32) {
    __syncthreads();  // previous iteration's fragment reads complete
    #pragma unroll
    for (int i = 0; i < 2; ++i) {   // A: 8 insts, 2/wave
      const int inst = 2 * w + i;
      const int r = inst * 16 + (l >> 2);
      const int cb = (l & 3) * 8;
      gload_lds16(A + (size_t)(row0 + r) * K + k0 + cb, &smA[inst * 512]);
    }
    #pragma unroll
    for (int i = 0; i < NBI; ++i) { // B: BN/16 insts, NBI/wave
      const int inst = NBI * w + i;
      const int r = inst * 16 + (l >> 2);
      const int cb = (l & 3) * 8;
      gload_lds16(Bt + (size_t)(col0 + r) * K + k0 + cb, &smB[inst * 512]);
    }
    __syncthreads();  // waits vmcnt(0): tiles resident

    bf16x8 af[4], bfr[NFR];
    #pragma unroll
    for (int m = 0; m < 4; ++m)
      af[m] = *(const bf16x8*)&smA[(wm + m * 16 + lr) * 32 + lg * 8];
    #pragma unroll
    for (int n = 0; n < NFR; ++n)
      bfr[n] = *(const bf16x8*)&smB[(wn + n * 16 + lr) * 32 + lg * 8];
    #pragma unroll
    for (int m = 0; m < 4; ++m)
      #pragma unroll
      for (int n = 0; n < NFR; ++n)
        acc[m][n] = __builtin_amdgcn_mfma_f32_16x16x32_bf16(af[m], bfr[n], acc[m][n], 0, 0, 0);
  }

  #pragma unroll
  for (int m = 0; m < 4; ++m) {
    #pragma unroll
    for (int n = 0; n < NFR; ++n) {
      const int col = col0 + wn + n * 16 + lr;
      const float bv = bias[col];
      #pragma unroll
      for (int r = 0; r < 4; ++r) {
        const int row = row0 + wm + m * 16 + lg * 4 + r;
        cstore(&C[(size_t)row * N + col], acc[m][n][r] + bv);
      }
    }
  }
}

// ---------------- Causal flash attention, bf16 MFMA ----------------
// r18 kernel + T5 setprio around the MFMA clusters (r20). 512 blocks x
// 512 threads (8 waves), waves 0-3 own q-tile lo=x, waves 4-7 own
// hi=31-x, one k-loop of 32-x tiles (lo active while kti <= x). K/V
// staged once/tile by threads <256. XCD-pinned bh; sigma-permuted K rows
// (PV A-frag packs in-lane); log2 softmax + defer-max; zero cross-lane
// common softmax path; LDS dbuf; 1 barrier/tile.
// T5 rationale: waves have asymmetric roles (hi compute / lo stage+idle)
// -- m191's prerequisite; m190's GEMM null was lockstep waves.
// [r14: intra-wave T15 regressed; r16: KVBLK=128 regressed; r17: 32
//  rows/wave at 4 waves regressed -- kernel is latency-bound.]
// sigma(rho) = 32*(rho>>5)+8*((rho>>2)&3)+4*((rho>>4)&1)+(rho&3).
__global__ __launch_bounds__(512, 4) void attn_fwd_mfma(
    const unsigned short* __restrict__ qkv, unsigned short* __restrict__ attn_out) {
  const int bid = blockIdx.x;           // 0..511
  const int xcd = bid & 7;
  const int li  = bid >> 3;             // 0..63 within XCD
  const int bh  = xcd * 4 + (li >> 4);  // 4 bh per XCD
  const int x   = li & 15;              // pair index: lo q-tile x, hi 31-x
  const int b = bh / H_, h = bh % H_;
  const unsigned short* base = qkv + (size_t)b * S_ * QKV_LD;

  __shared__ __align__(16) char smK[2][64 * 128];  // K tile [sigma-row][d], XOR-swizzled
  __shared__ __align__(16) char smV[2][64 * 128];  // V^T tile [d][k]

  const int t  = threadIdx.x;           // 0..511
  const int w  = t >> 6;                // 0..7
  const bool lo = (w < 4);
  const int wq = w & 3;
  const int l  = t & 63;
  const int lg = l >> 4;
  const int lr = l & 15;

  const int qt  = lo ? x : (31 - x);
  const int qw0 = qt * 64 + wq * 16;    // wave owns rows qw0..qw0+15

  const unsigned short* kbase = base + D_ + h * DH_;
  const unsigned short* vbase = base + 2 * D_ + h * DH_;

  // staging (threads <256 only): T14 async split, issue early / write late
  us8 kreg[2], vreg[2];
  const int kp  = (t & 31) * 2;          // V: pair of k-columns
  const int vdb = ((t >> 5) & 7) * 8;    // V: 8 d-rows

  auto issue_loads = [&](int k0) {
    #pragma unroll
    for (int it = 0; it < 2; ++it) {
      int idx = t + it * 256;
      int r = idx >> 3, c = idx & 7;
      kreg[it] = *(const us8*)(kbase + (size_t)(k0 + r) * QKV_LD + c * 8);
    }
    vreg[0] = *(const us8*)(vbase + (size_t)(k0 + kp) * QKV_LD + vdb);
    vreg[1] = *(const us8*)(vbase + (size_t)(k0 + kp + 1) * QKV_LD + vdb);
  };
  auto write_lds = [&](int buf) {
    #pragma unroll
    for (int it = 0; it < 2; ++it) {
      int idx = t + it * 256;
      int r = idx >> 3, c = idx & 7;
      // sigma^-1: global k-row r -> LDS row rho (pure bit permutation)
      int rho = (r & 0x23) | ((r & 0x04) << 2) | ((r & 0x18) >> 1);
      *(us8*)(smK[buf] + rho * 128 + ((c * 16) ^ ((rho & 7) << 4))) = kreg[it];
    }
    #pragma unroll
    for (int j = 0; j < 8; ++j) {
      int row = vdb + j;
      unsigned int pv = (unsigned int)vreg[0][j] | ((unsigned int)vreg[1][j] << 16);
      *(unsigned int*)(smV[buf] + row * 128 + ((2 * kp) ^ ((row & 7) << 4))) = pv;
    }
  };

  // ---- Q fragments (scale = 1/8 * log2(e): softmax in log2 domain) ----
  bf16x8 qf[2];
  {
    const unsigned short* qp = base + (size_t)(qw0 + lr) * QKV_LD + h * DH_ + 8 * lg;
    #pragma unroll
    for (int ks = 0; ks < 2; ++ks) {
      us8 qv = *(const us8*)(qp + 32 * ks);
      #pragma unroll
      for (int e = 0; e < 8; ++e) qf[ks][e] = (__bf16)(bf2f(qv[e]) * 0.18033688f);
    }
  }

  float mrun = -1e30f, lrun = 0.f;   // lrun = per-lane PARTIAL sum (r18)
  f32x4 acc_o[4] = {};

  const int ntiles = 32 - x;   // hi's tile count (superset of lo's x+1)
  if (t < 256) { issue_loads(0); write_lds(0); }
  __syncthreads();

  for (int kti = 0; kti < ntiles; ++kti) {
    const int k0 = kti * 64;
    const int cur = kti & 1;

    if (t < 256 && kti + 1 < ntiles) issue_loads((kti + 1) * 64);

    const bool active = lo ? (kti <= x) : true;   // wave-uniform
    if (active) {
      // ---- swapped QK^T on sigma-permuted K rows (T5: prio up) ----
      f32x4 sc[4] = {};
      __builtin_amdgcn_s_setprio(1);
      #pragma unroll
      for (int kt = 0; kt < 4; ++kt)
        #pragma unroll
        for (int ks = 0; ks < 2; ++ks) {
          int row = kt * 16 + lr;
          bf16x8 kb_ = *(const bf16x8*)(smK[cur] + row * 128 +
                                        (((ks * 64) + 16 * lg) ^ ((row & 7) << 4)));
          sc[kt] = __builtin_amdgcn_mfma_f32_16x16x32_bf16(kb_, qf[ks], sc[kt], 0, 0, 0);
        }
      __builtin_amdgcn_s_setprio(0);

      // ---- causal mask: sc[kt][r] true k = k0+32*(kt>>1)+8*lg+4*(kt&1)+r ----
      if (k0 + 63 > qw0) {
        #pragma unroll
        for (int kt = 0; kt < 4; ++kt)
          #pragma unroll
          for (int r = 0; r < 4; ++r) {
            int kc = k0 + ((kt >> 1) << 5) + (lg << 3) + ((kt & 1) << 2) + r;
            if (kc > qw0 + lr) sc[kt][r] = -1e30f;
          }
      }

      // ---- online softmax (log2 domain), zero cross-lane common path ----
      float v = fmaxf(fmaxf(sc[0][0], sc[0][1]), fmaxf(sc[0][2], sc[0][3]));
      #pragma unroll
      for (int kt = 1; kt < 4; ++kt)
        v = fmaxf(v, fmaxf(fmaxf(sc[kt][0], sc[kt][1]), fmaxf(sc[kt][2], sc[kt][3])));
      // defer-max on the IN-LANE max: if every lane's local max is within
      // threshold, the row max is too (equally conservative, no shfl).
      if (!__all(v <= mrun + 8.0f)) {
        v = fmaxf(v, __shfl_xor(v, 16));       // full row reduce (rare path)
        v = fmaxf(v, __shfl_xor(v, 32));
        const float mnew = fmaxf(mrun, v);
        const float alpha = exp2f(mrun - mnew);  // row-uniform
        mrun = mnew;
        float alphaO[4];
        #pragma unroll
        for (int r = 0; r < 4; ++r)
          alphaO[r] = __shfl(alpha, (l & 48) | (lg * 4 + r));
        #pragma unroll
        for (int dt = 0; dt < 4; ++dt)
          #pragma unroll
          for (int r = 0; r < 4; ++r) acc_o[dt][r] *= alphaO[r];
        lrun *= alpha;                           // partial sum scales uniformly
      }
      float s = 0.f;
      #pragma unroll
      for (int kt = 0; kt < 4; ++kt)
        #pragma unroll
        for (int r = 0; r < 4; ++r) {
          float p = exp2f(sc[kt][r] - mrun);
          sc[kt][r] = p;
          s += p;
        }
      lrun += s;                                 // no per-tile reduce (r18)

      // ---- PV A-fragments: pure in-lane pack (sigma made slots line up) ----
      union { unsigned int u[4]; bf16x8 v8; } pa[2];
      #pragma unroll
      for (int ks = 0; ks < 2; ++ks) {
        pa[ks].u[0] = pk2bf(sc[2 * ks][0], sc[2 * ks][1]);
        pa[ks].u[1] = pk2bf(sc[2 * ks][2], sc[2 * ks][3]);
        pa[ks].u[2] = pk2bf(sc[2 * ks + 1][0], sc[2 * ks + 1][1]);
        pa[ks].u[3] = pk2bf(sc[2 * ks + 1][2], sc[2 * ks + 1][3]);
      }

      // ---- PV (T5: prio up) ----
      __builtin_amdgcn_s_setprio(1);
      #pragma unroll
      for (int dt = 0; dt < 4; ++dt)
        #pragma unroll
        for (int ks = 0; ks < 2; ++ks) {
          int row = dt * 16 + lr;
          bf16x8 vb = *(const bf16x8*)(smV[cur] + row * 128 +
                                       (((ks * 64) + 16 * lg) ^ ((row & 7) << 4)));
          acc_o[dt] = __builtin_amdgcn_mfma_f32_16x16x32_bf16(pa[ks].v8, vb, acc_o[dt], 0, 0, 0);
        }
      __builtin_amdgcn_s_setprio(0);
    }

    if (t < 256 && kti + 1 < ntiles) write_lds(cur ^ 1);  // buf cur^1 free since barrier
    __syncthreads();
  }

  // ---- final row-sum reduce (once), normalize, write out (bf16) ----
  float ltot = lrun;
  ltot += __shfl_xor(ltot, 16);
  ltot += __shfl_xor(ltot, 32);
  const float inv = 1.0f / ltot;   // for q-row qw0+lr
  float invO[4];
  #pragma unroll
  for (int r = 0; r < 4; ++r)
    invO[r] = __shfl(inv, (l & 48) | (lg * 4 + r));
  #pragma unroll
  for (int dt = 0; dt < 4; ++dt)
    #pragma unroll
    for (int r = 0; r < 4; ++r)
      attn_out[(size_t)(b * S_ + qw0 + lg * 4 + r) * D_ + h * DH_ + dt * 16 + lr] =
          f2bf(acc_o[dt][r] * invO[r]);
}

extern "C" void kernel_launch(void* const* d_in, const int* in_sizes, int n_in,
                              void* d_out, int out_size, void* d_ws, size_t ws_size,
                              hipStream_t stream) {
  const float* x     = (const float*)d_in[0];
  const float* W_qkv = (const float*)d_in[1];
  const float* b_qkv = (const float*)d_in[2];
  const float* W_out = (const float*)d_in[3];
  const float* b_out = (const float*)d_in[4];
  float* out = (float*)d_out;

  char* ws = (char*)d_ws;
  unsigned short* qkv_bf  = (unsigned short*)ws;  ws += (size_t)M_ * QKV_LD * 2;
  unsigned short* attn_bf = (unsigned short*)ws;  ws += (size_t)M_ * D_ * 2;
  unsigned short* x_bf    = (unsigned short*)ws;  ws += (size_t)M_ * D_ * 2;
  unsigned short* wqkvT   = (unsigned short*)ws;  ws += (size_t)QKV_LD * D_ * 2;
  unsigned short* woutT   = (unsigned short*)ws;

  dim3 blk(256);
  // fused prep: conv (4096 blocks) + W_qkv^T (3072) + W_out^T (1024)
  prep_all<<<4096 + 3072 + 1024, blk, 0, stream>>>(x, x_bf, W_qkv, wqkvT, W_out, woutT);
  // QKV: 128x128 tile, grid (24,32)=768 blocks (3/CU)
  gemm_bf16_tn<128, unsigned short><<<dim3(QKV_LD / 128, M_ / 128), blk, 0, stream>>>(
      x_bf, wqkvT, b_qkv, qkv_bf, QKV_LD, D_);
  // lo/hi wave-split balanced pairing + XCD-pinned bh (r18 kernel + T5)
  attn_fwd_mfma<<<dim3(512), dim3(512), 0, stream>>>(qkv_bf, attn_bf);
  // out-proj: 128x64 tile, grid (16,32)=512 blocks (2/CU)
  gemm_bf16_tn<64, float><<<dim3(D_ / 64, M_ / 128), blk, 0, stream>>>(
      attn_bf, woutT, b_out, out, D_, D_);
}